// Round 12
// baseline (11115.132 us; speedup 1.0000x reference)
//
#include <hip/hip_runtime.h>
#include <hip/hip_bf16.h>

typedef __attribute__((ext_vector_type(8))) short bf16x8;
typedef __attribute__((ext_vector_type(8))) unsigned short u16x8;
typedef __attribute__((ext_vector_type(4))) float f32x4;

#define B_   4
#define S_   2048
#define H_   16
#define DKV  64
#define DM   1024

static __device__ __forceinline__ f32x4 mfma16(bf16x8 a, bf16x8 b, f32x4 c){
  return __builtin_amdgcn_mfma_f32_16x16x32_bf16(a, b, c, 0, 0, 0);
}
static __device__ __forceinline__ unsigned short f2b(float f){
  union { __hip_bfloat16 b; unsigned short u; } x;
  x.b = __float2bfloat16(f);
  return x.u;
}
static __device__ __forceinline__ float b2f(unsigned short u){
  union { unsigned int i; float f; } x;
  x.i = ((unsigned int)u) << 16;
  return x.f;
}

// ---------------- cast hidden fp32 -> bf16 ----------------
__global__ void cast_h_kernel(const float* __restrict__ in, unsigned short* __restrict__ out, int n4){
  int i = blockIdx.x * 256 + threadIdx.x;
  if (i >= n4) return;
  float4 v = reinterpret_cast<const float4*>(in)[i];
  ushort4 r;
  r.x = f2b(v.x); r.y = f2b(v.y); r.z = f2b(v.z); r.w = f2b(v.w);
  reinterpret_cast<ushort4*>(out)[i] = r;
}

// ---------------- transpose+cast the 4 weight matrices ----------------
__global__ void transpose_w_kernel(const float* __restrict__ w0, const float* __restrict__ w1,
                                   const float* __restrict__ w2, const float* __restrict__ w3,
                                   unsigned short* o0, unsigned short* o1,
                                   unsigned short* o2, unsigned short* o3){
  int z = blockIdx.z;
  const float* src = (z==0) ? w0 : (z==1) ? w1 : (z==2) ? w2 : w3;
  unsigned short* dst = (z==0) ? o0 : (z==1) ? o1 : (z==2) ? o2 : o3;
  __shared__ float tile[32][33];
  int bx = blockIdx.x * 32, by = blockIdx.y * 32;
  int tx = threadIdx.x, ty = threadIdx.y;
  #pragma unroll
  for (int i = 0; i < 32; i += 8)
    tile[ty + i][tx] = src[(size_t)(by + ty + i) * DM + bx + tx];
  __syncthreads();
  #pragma unroll
  for (int i = 0; i < 32; i += 8)
    dst[(size_t)(bx + ty + i) * DM + by + tx] = f2b(tile[tx][ty + i]);
}

// ---------------- build bias table: table_t[h][rel+2047] (used by attn only) ----------------
__global__ void build_table_kernel(const float* __restrict__ rel_bias, float* __restrict__ table_t){
  int i = blockIdx.x * 256 + threadIdx.x;
  if (i >= 16 * 4095) return;
  int h = i / 4095;
  int idx = i - h * 4095;
  int rel = idx - 2047;                 // memory - query
  int bucket = (rel > 0) ? 16 : 0;
  int rp = (rel < 0) ? -rel : rel;
  int off;
  if (rp < 8) off = rp;
  else off = 8 + (rp>=12) + (rp>=16) + (rp>=23) + (rp>=32) + (rp>=46) + (rp>=64) + (rp>=91);
  table_t[i] = rel_bias[(bucket + off) * 16 + h];
}

// ---------------- position bias writer: PB[b][h][q][k]  (fp32) ----------------
// RACE FIX (R12): reads rel_bias INPUT directly (32 values for this block's h
// cached in LDS) + inline integer bucketing. No dependence on scratch that
// lives inside the PB region being overwritten.
__global__ void posbias_kernel(const float* __restrict__ relb, const float* __restrict__ mask,
                               float* __restrict__ out){
  __shared__ float rbh[32];
  int row = blockIdx.x;                 // (b*16+h)*2048 + q
  int q = row & (S_ - 1);
  int h = (row >> 11) & (H_ - 1);
  int b = row >> 15;
  int tid = threadIdx.x;
  if (tid < 32) rbh[tid] = relb[tid * 16 + h];
  __syncthreads();
  const float* mrow = mask + b * S_;
  float* orow = out + (size_t)row * S_;
  int k0 = tid * 8;
  #pragma unroll
  for (int c = 0; c < 2; ++c){
    float4 mv = *(const float4*)(mrow + k0 + c * 4);
    float4 v;
    #pragma unroll
    for (int j = 0; j < 4; ++j){
      int k = k0 + c * 4 + j;
      int rel = k - q;
      int bucket = (rel > 0) ? 16 : 0;
      int rp = (rel < 0) ? -rel : rel;
      int off = (rp < 8) ? rp
              : 8 + (rp>=12) + (rp>=16) + (rp>=23) + (rp>=32) + (rp>=46) + (rp>=64) + (rp>=91);
      (&v.x)[j] = rbh[bucket + off] + (&mv.x)[j];
    }
    *(float4*)(orow + k0 + c*4) = v;
  }
}

// ---------------- bf16 GEMM: C = A[M,K] @ Bt[N,K]^T ----------------
// Reg-staged LDS (padded stride 40 elems = 80 B). Crash-free since R6.
// MODE 0: FP32 row-major out [M,N]
// MODE 1: bf16 scatter to [B,H,S,D]   (q/k/v; scale applied)
template<int MODE>
__global__ __launch_bounds__(256, 2) void gemm_bt_kernel(
    const unsigned short* __restrict__ A, const unsigned short* __restrict__ Bt,
    void* __restrict__ outp, int M, int N, int K, float scale)
{
  __shared__ __align__(16) unsigned short As[128 * 40];   // row stride 80 B
  __shared__ __align__(16) unsigned short Bs[128 * 40];
  int tid = threadIdx.x; int lane = tid & 63; int w = tid >> 6;
  int wr = w >> 1, wc = w & 1;
  int n0 = blockIdx.x * 128, m0 = blockIdx.y * 128;
  const char* Ab = (const char*)A;
  const char* Bb = (const char*)Bt;
  size_t Kb = (size_t)K * 2;

  int srow = (tid * 16) >> 6;        // 0..63
  int scolb = (tid * 16) & 63;       // 0/16/32/48

  f32x4 acc[4][4];
  #pragma unroll
  for (int i = 0; i < 4; ++i)
    #pragma unroll
    for (int j = 0; j < 4; ++j) acc[i][j] = (f32x4){0.f, 0.f, 0.f, 0.f};

  bf16x8 ar[2], br[2];
  auto gload = [&](int kt){
    size_t k0b = (size_t)kt * 64;
    #pragma unroll
    for (int c = 0; c < 2; ++c){
      int row = srow + c * 64;
      ar[c] = *(const bf16x8*)(Ab + (size_t)(m0 + row) * Kb + k0b + scolb);
      br[c] = *(const bf16x8*)(Bb + (size_t)(n0 + row) * Kb + k0b + scolb);
    }
  };
  auto lwrite = [&](){
    #pragma unroll
    for (int c = 0; c < 2; ++c){
      int row = srow + c * 64;
      *(bf16x8*)((char*)As + row * 80 + scolb) = ar[c];
      *(bf16x8*)((char*)Bs + row * 80 + scolb) = br[c];
    }
  };

  int nk = K >> 5;
  gload(0);
  lwrite();
  for (int kt = 0; kt < nk; ++kt){
    __syncthreads();
    if (kt + 1 < nk) gload(kt + 1);
    bf16x8 af[4], bfr[4];
    #pragma unroll
    for (int f = 0; f < 4; ++f){
      int row = wr * 64 + f * 16 + (lane & 15);
      af[f] = *(const bf16x8*)((const char*)As + row * 80 + (lane >> 4) * 16);
    }
    #pragma unroll
    for (int f = 0; f < 4; ++f){
      int row = wc * 64 + f * 16 + (lane & 15);
      bfr[f] = *(const bf16x8*)((const char*)Bs + row * 80 + (lane >> 4) * 16);
    }
    #pragma unroll
    for (int i = 0; i < 4; ++i)
      #pragma unroll
      for (int j = 0; j < 4; ++j)
        acc[i][j] = mfma16(af[i], bfr[j], acc[i][j]);
    __syncthreads();
    if (kt + 1 < nk) lwrite();
  }

  #pragma unroll
  for (int i = 0; i < 4; ++i){
    #pragma unroll
    for (int j = 0; j < 4; ++j){
      #pragma unroll
      for (int r = 0; r < 4; ++r){
        int m = m0 + wr * 64 + i * 16 + ((lane >> 4) * 4) + r;
        int n = n0 + wc * 64 + j * 16 + (lane & 15);
        float v = acc[i][j][r] * scale;
        if (MODE == 0){
          ((float*)outp)[(size_t)m * N + n] = v;
        } else {
          int b = m >> 11, s = m & 2047, hh = n >> 6, d = n & 63;
          ((unsigned short*)outp)[(((size_t)(b * H_ + hh) * S_) + s) * DKV + d] = f2b(v);
        }
      }
    }
  }
}

// ---------------- naive attention (crash-safe baseline) ----------------
__global__ __launch_bounds__(256) void attn_naive_kernel(
    const unsigned short* __restrict__ Qp, const unsigned short* __restrict__ Kp,
    const unsigned short* __restrict__ Vp, const float* __restrict__ table_t,
    const float* __restrict__ mask, unsigned short* __restrict__ outp)
{
  int w = threadIdx.x >> 6, lane = threadIdx.x & 63;
  int row = blockIdx.x * 4 + w;            // [0, B*H*S)
  int q = row & (S_ - 1), h = (row >> 11) & (H_ - 1), b = row >> 15;
  const unsigned short* qrow  = Qp + ((size_t)(b * H_ + h) * S_ + q) * DKV;
  const unsigned short* kbase = Kp + (size_t)(b * H_ + h) * S_ * DKV;
  const unsigned short* vbase = Vp + (size_t)(b * H_ + h) * S_ * DKV;
  const float* trow = table_t + h * 4095 + (2047 - q);
  const float* mrow = mask + b * S_;

  float qv[64];
  #pragma unroll
  for (int d0 = 0; d0 < 8; ++d0){
    u16x8 t = *(const u16x8*)(qrow + d0 * 8);
    #pragma unroll
    for (int j = 0; j < 8; ++j) qv[d0*8 + j] = b2f(t[j]);
  }

  float m = -1e30f;
  for (int i = 0; i < 32; ++i){
    int key = lane + i * 64;
    const unsigned short* krow = kbase + (size_t)key * DKV;
    float s = 0.f;
    #pragma unroll
    for (int d0 = 0; d0 < 8; ++d0){
      u16x8 t = *(const u16x8*)(krow + d0 * 8);
      #pragma unroll
      for (int j = 0; j < 8; ++j) s += qv[d0*8 + j] * b2f(t[j]);
    }
    s += trow[key] + mrow[key];
    m = fmaxf(m, s);
  }
  #pragma unroll
  for (int off = 1; off < 64; off <<= 1) m = fmaxf(m, __shfl_xor(m, off, 64));

  float lsum = 0.f;
  float o[64];
  #pragma unroll
  for (int d = 0; d < 64; ++d) o[d] = 0.f;
  for (int i = 0; i < 32; ++i){
    int key = lane + i * 64;
    const unsigned short* krow = kbase + (size_t)key * DKV;
    float s = 0.f;
    #pragma unroll
    for (int d0 = 0; d0 < 8; ++d0){
      u16x8 t = *(const u16x8*)(krow + d0 * 8);
      #pragma unroll
      for (int j = 0; j < 8; ++j) s += qv[d0*8 + j] * b2f(t[j]);
    }
    s += trow[key] + mrow[key];
    float p = __expf(s - m);
    lsum += p;
    const unsigned short* vrow = vbase + (size_t)key * DKV;
    #pragma unroll
    for (int d0 = 0; d0 < 8; ++d0){
      u16x8 t = *(const u16x8*)(vrow + d0 * 8);
      #pragma unroll
      for (int j = 0; j < 8; ++j) o[d0*8 + j] += p * b2f(t[j]);
    }
  }
  #pragma unroll
  for (int off = 1; off < 64; off <<= 1){
    lsum += __shfl_xor(lsum, off, 64);
    #pragma unroll
    for (int d = 0; d < 64; ++d) o[d] += __shfl_xor(o[d], off, 64);
  }
  if (lane == 0){
    float inv = 1.f / lsum;
    size_t off0 = ((size_t)b * S_ + q) * DM + h * DKV;
    #pragma unroll
    for (int d = 0; d < 64; ++d) outp[off0 + d] = f2b(o[d] * inv);
  }
}

extern "C" void kernel_launch(void* const* d_in, const int* in_sizes, int n_in,
                              void* d_out, int out_size, void* d_ws, size_t ws_size,
                              hipStream_t stream) {
  const float* hs   = (const float*)d_in[0];
  const float* msk  = (const float*)d_in[1];
  const float* wq   = (const float*)d_in[2];
  const float* wk   = (const float*)d_in[3];
  const float* wv   = (const float*)d_in[4];
  const float* wo   = (const float*)d_in[5];
  const float* relb = (const float*)d_in[6];

  // CONFIRMED MODEL (R11: Output 0 passed): d_out = 276,824,064 FP32, layout
  //   attn = d_out[0        : 8,388,608)   floats [4,2048,1024]
  //   PB   = d_out[8,388,608: 276,824,064) floats [4,16,2048,2048]
  // PB region doubles as scratch (~76 MB) during phases 1-5; posbias
  // overwrites it LAST and (R12 fix) reads only the rel_bias INPUT, so the
  // scratch-overwrite race is gone. d_ws untouched.
  float* out_attn = (float*)d_out;
  float* out_pb   = (float*)d_out + (size_t)B_ * S_ * DM;
  char* ws = (char*)out_pb;

  unsigned short* h_bf = (unsigned short*)(ws + 0);          // 16 MB, reused as attn_pre
  unsigned short* wq_t = (unsigned short*)(ws + 16777216);   // 2 MB each
  unsigned short* wk_t = (unsigned short*)(ws + 18874368);
  unsigned short* wv_t = (unsigned short*)(ws + 20971520);
  unsigned short* wo_t = (unsigned short*)(ws + 23068672);
  unsigned short* q_b  = (unsigned short*)(ws + 25165824);   // 16 MB each
  unsigned short* k_b  = (unsigned short*)(ws + 41943040);
  unsigned short* v_b  = (unsigned short*)(ws + 58720256);
  float*          tabl = (float*)(ws + 75497472);            // 262 KB (attn only)

  cast_h_kernel<<<8192, 256, 0, stream>>>(hs, h_bf, (B_ * S_ * DM) / 4);
  transpose_w_kernel<<<dim3(32, 32, 4), dim3(32, 8), 0, stream>>>(wq, wk, wv, wo,
                                                                  wq_t, wk_t, wv_t, wo_t);
  build_table_kernel<<<256, 256, 0, stream>>>(relb, tabl);

  gemm_bt_kernel<1><<<dim3(8, 64), 256, 0, stream>>>(h_bf, wq_t, q_b, 8192, 1024, 1024, 0.125f);
  gemm_bt_kernel<1><<<dim3(8, 64), 256, 0, stream>>>(h_bf, wk_t, k_b, 8192, 1024, 1024, 1.0f);
  gemm_bt_kernel<1><<<dim3(8, 64), 256, 0, stream>>>(h_bf, wv_t, v_b, 8192, 1024, 1024, 1.0f);

  attn_naive_kernel<<<(B_ * H_ * S_) / 4, 256, 0, stream>>>(q_b, k_b, v_b, tabl, msk, h_bf);

  gemm_bt_kernel<0><<<dim3(8, 64), 256, 0, stream>>>(h_bf, wo_t, out_attn, 8192, 1024, 1024, 1.0f);

  // LAST: overwrite the scratch region with the real position_bias (fp32),
  // reading only the rel_bias input (race-free).
  posbias_kernel<<<B_ * H_ * S_, 256, 0, stream>>>(relb, msk, out_pb);
}

// Round 13
// 540.839 us; speedup vs baseline: 20.5516x; 20.5516x over previous
//
#include <hip/hip_runtime.h>
#include <hip/hip_bf16.h>

typedef __attribute__((ext_vector_type(8))) short bf16x8;
typedef __attribute__((ext_vector_type(8))) unsigned short u16x8;
typedef __attribute__((ext_vector_type(4))) float f32x4;

#define B_   4
#define S_   2048
#define H_   16
#define DKV  64
#define DM   1024

static __device__ __forceinline__ f32x4 mfma16(bf16x8 a, bf16x8 b, f32x4 c){
  return __builtin_amdgcn_mfma_f32_16x16x32_bf16(a, b, c, 0, 0, 0);
}
static __device__ __forceinline__ unsigned short f2b(float f){
  union { __hip_bfloat16 b; unsigned short u; } x;
  x.b = __float2bfloat16(f);
  return x.u;
}

// ---------------- cast hidden fp32 -> bf16 ----------------
__global__ void cast_h_kernel(const float* __restrict__ in, unsigned short* __restrict__ out, int n4){
  int i = blockIdx.x * 256 + threadIdx.x;
  if (i >= n4) return;
  float4 v = reinterpret_cast<const float4*>(in)[i];
  ushort4 r;
  r.x = f2b(v.x); r.y = f2b(v.y); r.z = f2b(v.z); r.w = f2b(v.w);
  reinterpret_cast<ushort4*>(out)[i] = r;
}

// ---------------- transpose+cast the 4 weight matrices ----------------
__global__ void transpose_w_kernel(const float* __restrict__ w0, const float* __restrict__ w1,
                                   const float* __restrict__ w2, const float* __restrict__ w3,
                                   unsigned short* o0, unsigned short* o1,
                                   unsigned short* o2, unsigned short* o3){
  int z = blockIdx.z;
  const float* src = (z==0) ? w0 : (z==1) ? w1 : (z==2) ? w2 : w3;
  unsigned short* dst = (z==0) ? o0 : (z==1) ? o1 : (z==2) ? o2 : o3;
  __shared__ float tile[32][33];
  int bx = blockIdx.x * 32, by = blockIdx.y * 32;
  int tx = threadIdx.x, ty = threadIdx.y;
  #pragma unroll
  for (int i = 0; i < 32; i += 8)
    tile[ty + i][tx] = src[(size_t)(by + ty + i) * DM + bx + tx];
  __syncthreads();
  #pragma unroll
  for (int i = 0; i < 32; i += 8)
    dst[(size_t)(bx + ty + i) * DM + by + tx] = f2b(tile[tx][ty + i]);
}

// ---------------- build bias table: table_t[h][rel+2047] (attn only) ----------------
__global__ void build_table_kernel(const float* __restrict__ rel_bias, float* __restrict__ table_t){
  int i = blockIdx.x * 256 + threadIdx.x;
  if (i >= 16 * 4095) return;
  int h = i / 4095;
  int idx = i - h * 4095;
  int rel = idx - 2047;                 // memory - query
  int bucket = (rel > 0) ? 16 : 0;
  int rp = (rel < 0) ? -rel : rel;
  int off;
  if (rp < 8) off = rp;
  else off = 8 + (rp>=12) + (rp>=16) + (rp>=23) + (rp>=32) + (rp>=46) + (rp>=64) + (rp>=91);
  table_t[i] = rel_bias[(bucket + off) * 16 + h];
}

// ---------------- position bias writer: PB[b][h][q][k]  (fp32, race-free) ----------------
__global__ void posbias_kernel(const float* __restrict__ relb, const float* __restrict__ mask,
                               float* __restrict__ out){
  __shared__ float rbh[32];
  int row = blockIdx.x;                 // (b*16+h)*2048 + q
  int q = row & (S_ - 1);
  int h = (row >> 11) & (H_ - 1);
  int b = row >> 15;
  int tid = threadIdx.x;
  if (tid < 32) rbh[tid] = relb[tid * 16 + h];
  __syncthreads();
  const float* mrow = mask + b * S_;
  float* orow = out + (size_t)row * S_;
  int k0 = tid * 8;
  #pragma unroll
  for (int c = 0; c < 2; ++c){
    float4 mv = *(const float4*)(mrow + k0 + c * 4);
    float4 v;
    #pragma unroll
    for (int j = 0; j < 4; ++j){
      int k = k0 + c * 4 + j;
      int rel = k - q;
      int bucket = (rel > 0) ? 16 : 0;
      int rp = (rel < 0) ? -rel : rel;
      int off = (rp < 8) ? rp
              : 8 + (rp>=12) + (rp>=16) + (rp>=23) + (rp>=32) + (rp>=46) + (rp>=64) + (rp>=91);
      (&v.x)[j] = rbh[bucket + off] + (&mv.x)[j];
    }
    *(float4*)(orow + k0 + c*4) = v;
  }
}

// ---------------- bf16 GEMM: C = A[M,K] @ Bt[N,K]^T ----------------
// MODE 0: FP32 row-major out [M,N];  MODE 1: bf16 scatter to [B,H,S,D]
template<int MODE>
__global__ __launch_bounds__(256, 2) void gemm_bt_kernel(
    const unsigned short* __restrict__ A, const unsigned short* __restrict__ Bt,
    void* __restrict__ outp, int M, int N, int K, float scale)
{
  __shared__ __align__(16) unsigned short As[128 * 40];   // row stride 80 B
  __shared__ __align__(16) unsigned short Bs[128 * 40];
  int tid = threadIdx.x; int lane = tid & 63; int w = tid >> 6;
  int wr = w >> 1, wc = w & 1;
  int n0 = blockIdx.x * 128, m0 = blockIdx.y * 128;
  const char* Ab = (const char*)A;
  const char* Bb = (const char*)Bt;
  size_t Kb = (size_t)K * 2;

  int srow = (tid * 16) >> 6;
  int scolb = (tid * 16) & 63;

  f32x4 acc[4][4];
  #pragma unroll
  for (int i = 0; i < 4; ++i)
    #pragma unroll
    for (int j = 0; j < 4; ++j) acc[i][j] = (f32x4){0.f, 0.f, 0.f, 0.f};

  bf16x8 ar[2], br[2];
  auto gload = [&](int kt){
    size_t k0b = (size_t)kt * 64;
    #pragma unroll
    for (int c = 0; c < 2; ++c){
      int row = srow + c * 64;
      ar[c] = *(const bf16x8*)(Ab + (size_t)(m0 + row) * Kb + k0b + scolb);
      br[c] = *(const bf16x8*)(Bb + (size_t)(n0 + row) * Kb + k0b + scolb);
    }
  };
  auto lwrite = [&](){
    #pragma unroll
    for (int c = 0; c < 2; ++c){
      int row = srow + c * 64;
      *(bf16x8*)((char*)As + row * 80 + scolb) = ar[c];
      *(bf16x8*)((char*)Bs + row * 80 + scolb) = br[c];
    }
  };

  int nk = K >> 5;
  gload(0);
  lwrite();
  for (int kt = 0; kt < nk; ++kt){
    __syncthreads();
    if (kt + 1 < nk) gload(kt + 1);
    bf16x8 af[4], bfr[4];
    #pragma unroll
    for (int f = 0; f < 4; ++f){
      int row = wr * 64 + f * 16 + (lane & 15);
      af[f] = *(const bf16x8*)((const char*)As + row * 80 + (lane >> 4) * 16);
    }
    #pragma unroll
    for (int f = 0; f < 4; ++f){
      int row = wc * 64 + f * 16 + (lane & 15);
      bfr[f] = *(const bf16x8*)((const char*)Bs + row * 80 + (lane >> 4) * 16);
    }
    #pragma unroll
    for (int i = 0; i < 4; ++i)
      #pragma unroll
      for (int j = 0; j < 4; ++j)
        acc[i][j] = mfma16(af[i], bfr[j], acc[i][j]);
    __syncthreads();
    if (kt + 1 < nk) lwrite();
  }

  #pragma unroll
  for (int i = 0; i < 4; ++i){
    #pragma unroll
    for (int j = 0; j < 4; ++j){
      #pragma unroll
      for (int r = 0; r < 4; ++r){
        int m = m0 + wr * 64 + i * 16 + ((lane >> 4) * 4) + r;
        int n = n0 + wc * 64 + j * 16 + (lane & 15);
        float v = acc[i][j][r] * scale;
        if (MODE == 0){
          ((float*)outp)[(size_t)m * N + n] = v;
        } else {
          int b = m >> 11, s = m & 2047, hh = n >> 6, d = n & 63;
          ((unsigned short*)outp)[(((size_t)(b * H_ + hh) * S_) + s) * DKV + d] = f2b(v);
        }
      }
    }
  }
}

// ---------------- MFMA flash attention ----------------
// grid: B*H*32 blocks, 256 threads (4 waves). Block: one (b,h), 64 q-rows.
// Single-buffered LDS, 2 barriers/tile; V transposed at LDS-write time.
__global__ __launch_bounds__(256, 2) void attn_mfma_kernel(
    const unsigned short* __restrict__ Qp, const unsigned short* __restrict__ Kp,
    const unsigned short* __restrict__ Vp, const float* __restrict__ table_t,
    const float* __restrict__ mask, unsigned short* __restrict__ outp)
{
  __shared__ __align__(16) unsigned short Ks[64][72];   // [key][d]   stride 144 B
  __shared__ __align__(16) unsigned short Vs[64][72];   // [d][key]   (V^T)
  __shared__ __align__(16) unsigned short Ps[4][16][72];// per-wave P [q][k]
  __shared__ float bias_s[127];
  __shared__ float mask_s[64];

  int bid = blockIdx.x;
  int qt = bid & 31; int h = (bid >> 5) & 15; int b = bid >> 9;
  int qb = qt * 64;
  const unsigned short* qptr = Qp + ((size_t)(b * H_ + h) * S_ + qb) * DKV;
  const unsigned short* kptr = Kp + (size_t)(b * H_ + h) * S_ * DKV;
  const unsigned short* vptr = Vp + (size_t)(b * H_ + h) * S_ * DKV;
  int tid = threadIdx.x; int lane = tid & 63; int w = tid >> 6;

  // Q fragments: wave w owns q-rows qb + w*16 + 0..15
  bf16x8 qf[2];
  {
    const unsigned short* qrow = qptr + (size_t)(w * 16 + (lane & 15)) * DKV + 8 * (lane >> 4);
    qf[0] = *(const bf16x8*)qrow;
    qf[1] = *(const bf16x8*)(qrow + 32);
  }
  float m_r[4], l_r[4];
  f32x4 o_acc[4];
  #pragma unroll
  for (int r = 0; r < 4; ++r){ m_r[r] = -1e30f; l_r[r] = 0.f; }
  #pragma unroll
  for (int d = 0; d < 4; ++d) o_acc[d] = (f32x4){0.f, 0.f, 0.f, 0.f};

  int bias_base = h * 4095 + (2047 - qb - 63);   // + k0 + idx, idx in [0,126]

  // staging: thread t -> key = t&63, d-chunk = (t>>6)*16 (32 B per thread)
  int skey = tid & 63;
  int sd0  = (tid >> 6) * 16;

  for (int k0 = 0; k0 < S_; k0 += 64){
    // issue global loads BEFORE the barrier (latency hides under prior MFMA)
    const unsigned short* krow = kptr + (size_t)(k0 + skey) * DKV + sd0;
    const unsigned short* vrow = vptr + (size_t)(k0 + skey) * DKV + sd0;
    u16x8 ka = *(const u16x8*)krow;
    u16x8 kb2 = *(const u16x8*)(krow + 8);
    u16x8 va = *(const u16x8*)vrow;
    u16x8 vb2 = *(const u16x8*)(vrow + 8);
    float biasr = (tid < 127) ? table_t[bias_base + k0 + tid] : 0.f;
    float maskr = (tid >= 128 && tid < 192) ? mask[b * S_ + k0 + (tid - 128)] : 0.f;

    __syncthreads();                     // prior tile's LDS reads complete
    *(u16x8*)&Ks[skey][sd0]     = ka;
    *(u16x8*)&Ks[skey][sd0 + 8] = kb2;
    #pragma unroll
    for (int j = 0; j < 8; ++j){         // V transposed into Vs[d][key]
      Vs[sd0 + j][skey]     = va[j];
      Vs[sd0 + 8 + j][skey] = vb2[j];
    }
    if (tid < 127) bias_s[tid] = biasr;
    else if (tid < 192) mask_s[tid - 128] = maskr;
    __syncthreads();                     // staged tile visible

    // QK^T: sc[kb] = 16 q-rows x 16 keys, accumulated over d=64
    f32x4 sc[4];
    #pragma unroll
    for (int kb = 0; kb < 4; ++kb){
      sc[kb] = (f32x4){0.f, 0.f, 0.f, 0.f};
      #pragma unroll
      for (int ks = 0; ks < 2; ++ks){
        int row = kb * 16 + (lane & 15);
        bf16x8 kf = *(const bf16x8*)&Ks[row][ks * 32 + (lane >> 4) * 8];
        sc[kb] = mfma16(qf[ks], kf, sc[kb]);
      }
    }
    // bias + mask + online softmax (C layout: col=key=lane&15, row=q=(lane>>4)*4+r)
    float t[4][4];
    float tmax[4] = {-1e30f, -1e30f, -1e30f, -1e30f};
    #pragma unroll
    for (int kb = 0; kb < 4; ++kb){
      int k_l = kb * 16 + (lane & 15);
      float mk = mask_s[k_l];
      #pragma unroll
      for (int r = 0; r < 4; ++r){
        int q_l = w * 16 + (lane >> 4) * 4 + r;
        float tv = sc[kb][r] + bias_s[k_l - q_l + 63] + mk;
        t[kb][r] = tv;
        tmax[r] = fmaxf(tmax[r], tv);
      }
    }
    #pragma unroll
    for (int r = 0; r < 4; ++r){
      #pragma unroll
      for (int off = 1; off < 16; off <<= 1)
        tmax[r] = fmaxf(tmax[r], __shfl_xor(tmax[r], off, 64));
    }
    float scl[4];
    #pragma unroll
    for (int r = 0; r < 4; ++r){
      float mn = fmaxf(m_r[r], tmax[r]);
      scl[r] = __expf(m_r[r] - mn);
      m_r[r] = mn;
    }
    float rs[4] = {0.f, 0.f, 0.f, 0.f};
    #pragma unroll
    for (int kb = 0; kb < 4; ++kb)
      #pragma unroll
      for (int r = 0; r < 4; ++r){
        float p = __expf(t[kb][r] - m_r[r]);
        t[kb][r] = p;
        rs[r] += p;
      }
    #pragma unroll
    for (int r = 0; r < 4; ++r){
      #pragma unroll
      for (int off = 1; off < 16; off <<= 1)
        rs[r] += __shfl_xor(rs[r], off, 64);
      l_r[r] = l_r[r] * scl[r] + rs[r];
      o_acc[0][r] *= scl[r]; o_acc[1][r] *= scl[r];
      o_acc[2][r] *= scl[r]; o_acc[3][r] *= scl[r];
    }
    // P -> per-wave LDS tile (transpose to A-fragment layout), then PV
    #pragma unroll
    for (int kb = 0; kb < 4; ++kb)
      #pragma unroll
      for (int r = 0; r < 4; ++r){
        int prow = (lane >> 4) * 4 + r;
        int pcol = kb * 16 + (lane & 15);
        Ps[w][prow][pcol] = f2b(t[kb][r]);
      }
    bf16x8 pa[2];
    #pragma unroll
    for (int ks = 0; ks < 2; ++ks)
      pa[ks] = *(const bf16x8*)&Ps[w][lane & 15][ks * 32 + (lane >> 4) * 8];
    #pragma unroll
    for (int db = 0; db < 4; ++db)
      #pragma unroll
      for (int ks = 0; ks < 2; ++ks){
        bf16x8 vf = *(const bf16x8*)&Vs[db * 16 + (lane & 15)][ks * 32 + (lane >> 4) * 8];
        o_acc[db] = mfma16(pa[ks], vf, o_acc[db]);
      }
  }

  #pragma unroll
  for (int r = 0; r < 4; ++r){
    float inv = 1.0f / l_r[r];
    int qg = qb + w * 16 + (lane >> 4) * 4 + r;
    size_t rowoff = ((size_t)b * S_ + qg) * DM + h * DKV;
    #pragma unroll
    for (int db = 0; db < 4; ++db)
      outp[rowoff + db * 16 + (lane & 15)] = f2b(o_acc[db][r] * inv);
  }
}

extern "C" void kernel_launch(void* const* d_in, const int* in_sizes, int n_in,
                              void* d_out, int out_size, void* d_ws, size_t ws_size,
                              hipStream_t stream) {
  const float* hs   = (const float*)d_in[0];
  const float* msk  = (const float*)d_in[1];
  const float* wq   = (const float*)d_in[2];
  const float* wk   = (const float*)d_in[3];
  const float* wv   = (const float*)d_in[4];
  const float* wo   = (const float*)d_in[5];
  const float* relb = (const float*)d_in[6];

  // CONFIRMED (R12 green): d_out = 276,824,064 FP32,
  //   attn = d_out[0:8,388,608), PB = d_out[8,388,608:276,824,064).
  // PB region doubles as scratch (~76 MB); posbias overwrites it LAST reading
  // only the rel_bias input. d_ws untouched.
  float* out_attn = (float*)d_out;
  float* out_pb   = (float*)d_out + (size_t)B_ * S_ * DM;
  char* ws = (char*)out_pb;

  unsigned short* h_bf = (unsigned short*)(ws + 0);          // 16 MB, reused as attn_pre
  unsigned short* wq_t = (unsigned short*)(ws + 16777216);
  unsigned short* wk_t = (unsigned short*)(ws + 18874368);
  unsigned short* wv_t = (unsigned short*)(ws + 20971520);
  unsigned short* wo_t = (unsigned short*)(ws + 23068672);
  unsigned short* q_b  = (unsigned short*)(ws + 25165824);
  unsigned short* k_b  = (unsigned short*)(ws + 41943040);
  unsigned short* v_b  = (unsigned short*)(ws + 58720256);
  float*          tabl = (float*)(ws + 75497472);            // attn only

  cast_h_kernel<<<8192, 256, 0, stream>>>(hs, h_bf, (B_ * S_ * DM) / 4);
  transpose_w_kernel<<<dim3(32, 32, 4), dim3(32, 8), 0, stream>>>(wq, wk, wv, wo,
                                                                  wq_t, wk_t, wv_t, wo_t);
  build_table_kernel<<<256, 256, 0, stream>>>(relb, tabl);

  gemm_bt_kernel<1><<<dim3(8, 64), 256, 0, stream>>>(h_bf, wq_t, q_b, 8192, 1024, 1024, 0.125f);
  gemm_bt_kernel<1><<<dim3(8, 64), 256, 0, stream>>>(h_bf, wk_t, k_b, 8192, 1024, 1024, 1.0f);
  gemm_bt_kernel<1><<<dim3(8, 64), 256, 0, stream>>>(h_bf, wv_t, v_b, 8192, 1024, 1024, 1.0f);

  attn_mfma_kernel<<<B_ * H_ * 32, 256, 0, stream>>>(q_b, k_b, v_b, tabl, msk, h_bf);

  gemm_bt_kernel<0><<<dim3(8, 64), 256, 0, stream>>>(h_bf, wo_t, out_attn, 8192, 1024, 1024, 1.0f);

  // LAST: real position_bias (fp32), race-free (reads rel_bias input only).
  posbias_kernel<<<B_ * H_ * S_, 256, 0, stream>>>(relb, msk, out_pb);
}